// Round 2
// baseline (431.589 us; speedup 1.0000x reference)
//
#include <hip/hip_runtime.h>

#define IMG_W 512
#define IMG_H 512
#define RH    32            // output rows per block-strip (1024 blocks -> 3 res/CU)
#define KS    11
#define KR    5
#define OFF   8             // LDS left pad (16B-aligned staging writes)
#define LROW  (OFF + IMG_W + OFF)   // 528 floats per row buffer
#define CH    KS            // 11 rows staged per barrier pair (ring-aligned)
#define NROWS (RH + 2*KR)   // 42 input rows per strip
#define NCH   4             // 4*11 = 44 >= 42

// One block = one 32-row x 512-col strip of one image.
// Chunked pipeline with T14 async-stage split: global loads for chunk c+1 are
// issued into registers right after chunk c is staged, so HBM/L3 latency hides
// under the 11-row compute phase. Horizontal 11-tap (5 fields) in registers,
// 11-row register ring, vertical 11-tap + SSIM in registers. Ring phase
// p == row mod 11 is compile-time.
__global__ __launch_bounds__(256, 3)
void ssim_main(const float* __restrict__ xhat,
               const float* __restrict__ x,
               const float* __restrict__ kern,
               float* __restrict__ accum)
{
    __shared__ float rowA[CH][LROW];   // a = (x+1)/2, zero-padded
    __shared__ float rowB[CH][LROW];   // b = (xhat+1)/2
    __shared__ float red[4];

    const int tid   = threadIdx.x;
    const int c0    = tid << 1;           // this thread's 2 columns
    const int img   = blockIdx.x >> 4;    // 16 strips per image
    const int strip = blockIdx.x & 15;
    const int R0    = strip * RH;
    const float* xp = x    + (size_t)img * (IMG_W * IMG_H);
    const float* hp = xhat + (size_t)img * (IMG_W * IMG_H);

    // Separable 1D weights from the rank-1 2D kernel: g[i] = k[5][i]/sqrt(k[5][5])
    float g[KS];
    {
        const float inv = rsqrtf(kern[5 * KS + 5]);
        #pragma unroll
        for (int i = 0; i < KS; ++i) g[i] = kern[5 * KS + i] * inv;
    }

    // zero all LDS once; staging only overwrites the interior, pads stay 0
    {
        float* fa = &rowA[0][0];
        float* fb = &rowB[0][0];
        for (int i = tid; i < CH * LROW; i += 256) { fa[i] = 0.f; fb[i] = 0.f; }
    }

    // staging role: threads 0..127 stage x -> rowA, 128..255 stage xhat -> rowB
    const bool isB = (tid >= 128);
    const float* sp = isB ? hp : xp;
    float* dstBase  = isB ? &rowB[0][0] : &rowA[0][0];
    const int c4    = (tid & 127) << 2;   // staged float4 column

    // ring buffer of horizontally-convolved rows: 5 fields x 11 rows x 2 cols
    float hist[5][KS][2];
    float acc = 0.f;
    const float C1 = 1e-4f, C2 = 9e-4f;

    // ---- prologue: prefetch chunk 0 into registers ----
    float4 pre[CH];
    #pragma unroll
    for (int j = 0; j < CH; ++j) {
        const int ri = R0 - KR + j;
        pre[j] = make_float4(0.f, 0.f, 0.f, 0.f);
        if (ri >= 0 && ri < IMG_H)
            pre[j] = *(const float4*)(sp + (size_t)ri * IMG_W + c4);
    }

    #pragma unroll 1
    for (int chk = 0; chk < NCH; ++chk) {
        __syncthreads();   // previous chunk fully consumed (and LDS zero-init done)

        // ---- write prefetched chunk to LDS (transform to [0,1]) ----
        #pragma unroll
        for (int j = 0; j < CH; ++j) {
            float4 s;
            s.x = fmaf(pre[j].x, 0.5f, 0.5f);
            s.y = fmaf(pre[j].y, 0.5f, 0.5f);
            s.z = fmaf(pre[j].z, 0.5f, 0.5f);
            s.w = fmaf(pre[j].w, 0.5f, 0.5f);
            *(float4*)(dstBase + j * LROW + OFF + c4) = s;  // 16B-aligned
        }
        __syncthreads();   // chunk staged

        // ---- issue next chunk's global loads NOW; latency hides under compute ----
        if (chk + 1 < NCH) {
            #pragma unroll
            for (int j = 0; j < CH; ++j) {
                const int ri = R0 - KR + (chk + 1) * CH + j;
                pre[j] = make_float4(0.f, 0.f, 0.f, 0.f);
                if (ri >= 0 && ri < IMG_H)
                    pre[j] = *(const float4*)(sp + (size_t)ri * IMG_W + c4);
            }
        }

        // ---- compute 11 rows; ring slot == p (compile-time) ----
        #pragma unroll
        for (int p = 0; p < CH; ++p) {
            const int rr = chk * CH + p;          // block-uniform
            if (rr < NROWS) {
                // window [c0-6, c0+7] as 7 aligned float2 (ds_read_b64)
                const int ib = OFF + c0 - 6;      // even -> 8B-aligned
                float wa[14], wb[14];
                #pragma unroll
                for (int m = 0; m < 7; ++m) {
                    const float2 ta = *(const float2*)&rowA[p][ib + 2 * m];
                    const float2 tb = *(const float2*)&rowB[p][ib + 2 * m];
                    wa[2 * m] = ta.x; wa[2 * m + 1] = ta.y;
                    wb[2 * m] = tb.x; wb[2 * m + 1] = tb.y;
                }

                // ---- horizontal pass: 5 fields, 2 columns ----
                float h[5][2];
                #pragma unroll
                for (int f = 0; f < 5; ++f) { h[f][0] = 0.f; h[f][1] = 0.f; }
                #pragma unroll
                for (int i = 0; i < KS + 1; ++i) {
                    const float pa  = wa[i + 1];   // col c0-5+i
                    const float pb  = wb[i + 1];
                    const float paa = pa * pa;
                    const float pbb = pb * pb;
                    const float pab = pa * pb;
                    if (i < KS) {                  // contributes to col 0
                        const float w = g[i];
                        h[0][0] = fmaf(w, pa,  h[0][0]);
                        h[1][0] = fmaf(w, pb,  h[1][0]);
                        h[2][0] = fmaf(w, paa, h[2][0]);
                        h[3][0] = fmaf(w, pbb, h[3][0]);
                        h[4][0] = fmaf(w, pab, h[4][0]);
                    }
                    if (i > 0) {                   // contributes to col 1
                        const float w = g[i - 1];
                        h[0][1] = fmaf(w, pa,  h[0][1]);
                        h[1][1] = fmaf(w, pb,  h[1][1]);
                        h[2][1] = fmaf(w, paa, h[2][1]);
                        h[3][1] = fmaf(w, pbb, h[3][1]);
                        h[4][1] = fmaf(w, pab, h[4][1]);
                    }
                }
                #pragma unroll
                for (int f = 0; f < 5; ++f) {
                    hist[f][p][0] = h[f][0];
                    hist[f][p][1] = h[f][1];
                }

                // ---- vertical pass + SSIM once ring is full ----
                if (rr >= 2 * KR) {
                    float v[5][2];
                    #pragma unroll
                    for (int f = 0; f < 5; ++f) { v[f][0] = 0.f; v[f][1] = 0.f; }
                    #pragma unroll
                    for (int t = 0; t < KS; ++t) {
                        const int slot = (p + 1 + t) % KS;   // compile-time
                        const float w = g[t];
                        #pragma unroll
                        for (int f = 0; f < 5; ++f) {
                            v[f][0] = fmaf(w, hist[f][slot][0], v[f][0]);
                            v[f][1] = fmaf(w, hist[f][slot][1], v[f][1]);
                        }
                    }
                    #pragma unroll
                    for (int col = 0; col < 2; ++col) {
                        const float mux  = v[0][col], muy = v[1][col];
                        const float mux2 = mux * mux;
                        const float muy2 = muy * muy;
                        const float muxy = mux * muy;
                        const float sx   = v[2][col] - mux2;
                        const float sy   = v[3][col] - muy2;
                        const float sxy  = v[4][col] - muxy;
                        const float num  = (2.f * muxy + C1) * (2.f * sxy + C2);
                        const float den  = (mux2 + muy2 + C1) * (sx + sy + C2);
                        acc = fmaf(num, __builtin_amdgcn_rcpf(den + 1e-8f), acc);
                    }
                }
            }
        }
    }

    // ---- block reduction: wave shuffle, then LDS across the 4 waves ----
    #pragma unroll
    for (int o = 32; o > 0; o >>= 1) acc += __shfl_down(acc, o, 64);
    if ((tid & 63) == 0) red[tid >> 6] = acc;
    __syncthreads();
    if (tid == 0) atomicAdd(accum, red[0] + red[1] + red[2] + red[3]);
}

__global__ void ssim_final(const float* __restrict__ accum,
                           float* __restrict__ out)
{
    out[0] = 1.0f - accum[0] * (1.0f / (64.0f * 512.0f * 512.0f));
}

extern "C" void kernel_launch(void* const* d_in, const int* in_sizes, int n_in,
                              void* d_out, int out_size, void* d_ws, size_t ws_size,
                              hipStream_t stream) {
    const float* xhat = (const float*)d_in[0];
    const float* xin  = (const float*)d_in[1];
    const float* kern = (const float*)d_in[2];
    float* out = (float*)d_out;
    float* ws  = (float*)d_ws;

    const int nimg   = in_sizes[0] / (IMG_W * IMG_H);   // 64
    const int strips = IMG_H / RH;                      // 16
    const int nblk   = nimg * strips;                   // 1024

    hipMemsetAsync(ws, 0, sizeof(float), stream);
    ssim_main<<<nblk, 256, 0, stream>>>(xhat, xin, kern, ws);
    ssim_final<<<1, 1, 0, stream>>>(ws, out);
}

// Round 3
// 212.974 us; speedup vs baseline: 2.0265x; 2.0265x over previous
//
#include <hip/hip_runtime.h>
#include <stdint.h>

#define IMG_W 512
#define IMG_H 512
#define RH    64            // output rows per block-strip
#define KS    11
#define KR    5
#define OFF   8             // LDS left pad (16B-aligned, stays zero)
#define LROW  (OFF + IMG_W + OFF)   // 528 floats per row buffer
#define CH    KS            // 11 rows per barrier pair (ring-aligned)
#define NROWS (RH + 2*KR)   // 74 input rows per strip
#define NCH   7             // 7*11 = 77 >= 74

// One block = 512 threads (8 waves), one 64-row x 512-col strip, 1 col/thread.
// Staging is direct global->LDS (global_load_lds_dwordx4): RAW values, zero
// VGPR cost. The (v+1)/2 shift is folded into the epilogue analytically:
//   mu_x = (U+1)/2,  sig_x = (U2 - U^2)/4,  sig_xy = (UV - U*V)/4
// where U = conv2(x), U2 = conv2(x^2), UV = conv2(x*xhat) on RAW inputs.
// Horizontal 11-tap (5 fields) in registers, 11-row register ring (55 VGPR),
// vertical 11-tap + SSIM in registers. Ring phase p is compile-time.
__global__ __launch_bounds__(512, 4)
void ssim_main(const float* __restrict__ xhat,
               const float* __restrict__ x,
               const float* __restrict__ kern,
               float* __restrict__ accum)
{
    __shared__ float rowA[CH][LROW];   // raw x rows, zero-padded cols
    __shared__ float rowB[CH][LROW];   // raw xhat rows
    __shared__ float red[8];

    const int tid   = threadIdx.x;
    const int lane  = tid & 63;
    const int wid   = tid >> 6;          // 8 waves
    const int c     = tid;               // this thread's column
    const int img   = blockIdx.x >> 3;   // 8 strips per image
    const int strip = blockIdx.x & 7;
    const int R0    = strip * RH;
    const float* xp = x    + (size_t)img * (IMG_W * IMG_H);
    const float* hp = xhat + (size_t)img * (IMG_W * IMG_H);

    // Separable 1D weights from the rank-1 2D kernel: g[i] = k[5][i]/sqrt(k[5][5])
    float g[KS];
    {
        const float inv = rsqrtf(kern[5 * KS + 5]);
        #pragma unroll
        for (int i = 0; i < KS; ++i) g[i] = kern[5 * KS + i] * inv;
    }

    // zero all LDS once (pads must stay 0; interior gets overwritten each chunk)
    {
        float4* a4 = (float4*)&rowA[0][0];
        float4* b4 = (float4*)&rowB[0][0];
        #pragma unroll 1
        for (int i = tid; i < (CH * LROW) / 4; i += 512) {
            a4[i] = make_float4(0.f, 0.f, 0.f, 0.f);
            b4[i] = make_float4(0.f, 0.f, 0.f, 0.f);
        }
    }

    // ring buffer of horizontally-convolved rows: 5 fields x 11 rows, 1 col
    float hist[5][KS];
    float acc = 0.f;
    const float C1 = 1e-4f, C2 = 9e-4f;

    #pragma unroll 1
    for (int chk = 0; chk < NCH; ++chk) {
        __syncthreads();   // previous chunk fully consumed (also covers zero-init)

        // ---- stage 11 rows x 2 fields, direct global->LDS ----
        // 44 issues = row j (0..10) x field f (A,B) x half h (0,1); issue q
        // maps j = q>>2, f = (q>>1)&1, h = q&1; wave w takes q = w, w+8, ...
        // Each issue: 64 lanes x 16B = 1024B, perfectly coalesced; LDS dest is
        // wave-uniform base + lane*16 (linear, matches layout).
        #pragma unroll
        for (int k = 0; k < 6; ++k) {
            const int q = wid + 8 * k;           // wave-uniform
            if (q < 4 * CH) {
                const int j  = q >> 2;
                const int rr = chk * CH + j;
                if (rr < NROWS) {
                    const int f  = (q >> 1) & 1;
                    const int h  = q & 1;
                    const int ri = R0 - KR + rr;
                    float* ldsbase = f ? &rowB[j][OFF + h * 256]
                                       : &rowA[j][OFF + h * 256];
                    if (ri >= 0 && ri < IMG_H) {
                        const float* gsrc = (f ? hp : xp)
                            + (size_t)ri * IMG_W + h * 256 + lane * 4;
                        __builtin_amdgcn_global_load_lds(
                            (const __attribute__((address_space(1))) void*)gsrc,
                            (__attribute__((address_space(3))) void*)ldsbase,
                            16, 0, 0);
                    } else {
                        *(float4*)(ldsbase + lane * 4) =
                            make_float4(0.f, 0.f, 0.f, 0.f);
                    }
                }
            }
        }
        __syncthreads();   // barrier waits vmcnt(0): chunk staged

        // ---- compute 11 rows; ring slot == p (compile-time) ----
        #pragma unroll
        for (int p = 0; p < CH; ++p) {
            const int rr = chk * CH + p;          // block-uniform
            if (rr < NROWS) {
                // window cols [c-6, c+6) as 6 aligned float2 (ds_read_b64);
                // tap t (col c-5+t) is element t+1
                const int ib = OFF + c - 6;       // even -> 8B-aligned
                float wa[12], wb[12];
                #pragma unroll
                for (int m = 0; m < 6; ++m) {
                    const float2 ta = *(const float2*)&rowA[p][ib + 2 * m];
                    const float2 tb = *(const float2*)&rowB[p][ib + 2 * m];
                    wa[2 * m] = ta.x; wa[2 * m + 1] = ta.y;
                    wb[2 * m] = tb.x; wb[2 * m + 1] = tb.y;
                }

                // ---- horizontal pass: 5 raw fields -> ring slot p ----
                float h0 = 0.f, h1 = 0.f, h2 = 0.f, h3 = 0.f, h4 = 0.f;
                #pragma unroll
                for (int t = 0; t < KS; ++t) {
                    const float w  = g[t];
                    const float pa = wa[t + 1];
                    const float pb = wb[t + 1];
                    h0 = fmaf(w, pa,      h0);
                    h1 = fmaf(w, pb,      h1);
                    h2 = fmaf(w, pa * pa, h2);
                    h3 = fmaf(w, pb * pb, h3);
                    h4 = fmaf(w, pa * pb, h4);
                }
                hist[0][p] = h0; hist[1][p] = h1; hist[2][p] = h2;
                hist[3][p] = h3; hist[4][p] = h4;

                // ---- vertical pass + SSIM once ring is full ----
                if (rr >= 2 * KR) {
                    float U = 0.f, V = 0.f, U2 = 0.f, V2 = 0.f, UVc = 0.f;
                    #pragma unroll
                    for (int t = 0; t < KS; ++t) {
                        const int slot = (p + 1 + t) % KS;   // compile-time
                        const float w = g[t];
                        U   = fmaf(w, hist[0][slot], U);
                        V   = fmaf(w, hist[1][slot], V);
                        U2  = fmaf(w, hist[2][slot], U2);
                        V2  = fmaf(w, hist[3][slot], V2);
                        UVc = fmaf(w, hist[4][slot], UVc);
                    }
                    // epilogue on raw-field moments (shift folded in):
                    const float pU = U + 1.f, pV = V + 1.f;
                    const float t1 = fmaf(0.5f,  pU * pV,            C1);
                    const float t2 = fmaf(0.5f,  fmaf(-U, V, UVc),   C2);
                    const float t3 = fmaf(0.25f, fmaf(pU, pU, pV*pV), C1);
                    const float e  = fmaf(-U, U, U2) + fmaf(-V, V, V2);
                    const float t4 = fmaf(0.25f, e,                  C2);
                    acc = fmaf(t1 * t2,
                               __builtin_amdgcn_rcpf(fmaf(t3, t4, 1e-8f)),
                               acc);
                }
            }
        }
    }

    // ---- block reduction: wave shuffle, then LDS across the 8 waves ----
    #pragma unroll
    for (int o = 32; o > 0; o >>= 1) acc += __shfl_down(acc, o, 64);
    if (lane == 0) red[wid] = acc;
    __syncthreads();
    if (tid == 0) {
        float s = 0.f;
        #pragma unroll
        for (int w = 0; w < 8; ++w) s += red[w];
        atomicAdd(accum, s);
    }
}

__global__ void ssim_final(const float* __restrict__ accum,
                           float* __restrict__ out)
{
    out[0] = 1.0f - accum[0] * (1.0f / (64.0f * 512.0f * 512.0f));
}

extern "C" void kernel_launch(void* const* d_in, const int* in_sizes, int n_in,
                              void* d_out, int out_size, void* d_ws, size_t ws_size,
                              hipStream_t stream) {
    const float* xhat = (const float*)d_in[0];
    const float* xin  = (const float*)d_in[1];
    const float* kern = (const float*)d_in[2];
    float* out = (float*)d_out;
    float* ws  = (float*)d_ws;

    const int nimg   = in_sizes[0] / (IMG_W * IMG_H);   // 64
    const int strips = IMG_H / RH;                      // 8
    const int nblk   = nimg * strips;                   // 512 = 2 blocks/CU

    hipMemsetAsync(ws, 0, sizeof(float), stream);
    ssim_main<<<nblk, 512, 0, stream>>>(xhat, xin, kern, ws);
    ssim_final<<<1, 1, 0, stream>>>(ws, out);
}

// Round 4
// 209.486 us; speedup vs baseline: 2.0602x; 1.0166x over previous
//
#include <hip/hip_runtime.h>
#include <stdint.h>

#define IMG_W 512
#define IMG_H 512
#define RH    64            // output rows per block-strip
#define KS    11
#define KR    5
#define OFF   8             // LDS left pad (16B-aligned, stays zero)
#define LROW  (OFF + IMG_W + OFF)   // 528 floats per row buffer
#define CH    KS            // 11 rows per barrier pair (ring-aligned)
#define NROWS (RH + 2*KR)   // 74 input rows per strip
#define NCH   7             // 7*11 = 77 >= 74

// One block = 512 threads (8 waves), one 64-row x 512-col strip, 1 col/thread.
// Staging is direct global->LDS (global_load_lds_dwordx4) of RAW values; the
// (v+1)/2 shift is folded into the epilogue analytically. 4-field ring:
//   U = conv(x), V = conv(xhat), S = conv(x^2 + xhat^2), P = conv(x*xhat)
// (sig_x+sig_y only ever appears summed, so the two square moments share one
// field — convolution is linear). Ring phase p is compile-time.
// __launch_bounds__(512,3): register budget ~168 so the 44-reg ring stays in
// arch VGPRs (at (512,4) the allocator chose the 64-VGPR tier and paid ~52
// v_accvgpr moves per row).
__global__ __launch_bounds__(512, 3)
void ssim_main(const float* __restrict__ xhat,
               const float* __restrict__ x,
               const float* __restrict__ kern,
               float* __restrict__ accum)
{
    __shared__ float rowA[CH][LROW];   // raw x rows, zero-padded cols
    __shared__ float rowB[CH][LROW];   // raw xhat rows
    __shared__ float red[8];

    const int tid   = threadIdx.x;
    const int lane  = tid & 63;
    const int wid   = tid >> 6;          // 8 waves
    const int c     = tid;               // this thread's column
    const int img   = blockIdx.x >> 3;   // 8 strips per image
    const int strip = blockIdx.x & 7;
    const int R0    = strip * RH;
    const float* xp = x    + (size_t)img * (IMG_W * IMG_H);
    const float* hp = xhat + (size_t)img * (IMG_W * IMG_H);

    // Separable 1D weights g[i] = k[5][i]/sqrt(k[5][5]); lane-uniform ->
    // pin to SGPRs via readfirstlane (saves 11 VGPRs of pressure).
    float g[KS];
    {
        const float inv = rsqrtf(kern[5 * KS + 5]);
        #pragma unroll
        for (int i = 0; i < KS; ++i) {
            const float v = kern[5 * KS + i] * inv;
            g[i] = __builtin_bit_cast(float,
                     __builtin_amdgcn_readfirstlane(__builtin_bit_cast(int, v)));
        }
    }

    // zero all LDS once (pads must stay 0; interior overwritten each chunk)
    {
        float4* a4 = (float4*)&rowA[0][0];
        float4* b4 = (float4*)&rowB[0][0];
        #pragma unroll 1
        for (int i = tid; i < (CH * LROW) / 4; i += 512) {
            a4[i] = make_float4(0.f, 0.f, 0.f, 0.f);
            b4[i] = make_float4(0.f, 0.f, 0.f, 0.f);
        }
    }

    // ring of horizontally-convolved rows: 4 fields x 11 rows (44 VGPRs)
    float hist[4][KS];
    float acc = 0.f;
    const float C1 = 1e-4f, C2 = 9e-4f;

    #pragma unroll 1
    for (int chk = 0; chk < NCH; ++chk) {
        __syncthreads();   // previous chunk fully consumed (also covers zero-init)

        // ---- stage 11 rows x 2 fields, direct global->LDS ----
        // 44 issues = row j (0..10) x field f (A,B) x half h (0,1); wave w
        // takes q = w, w+8, ... Each issue: 64 lanes x 16B, coalesced; LDS
        // dest is wave-uniform base + lane*16 (linear layout).
        #pragma unroll
        for (int k = 0; k < 6; ++k) {
            const int q = wid + 8 * k;           // wave-uniform
            if (q < 4 * CH) {
                const int j  = q >> 2;
                const int rr = chk * CH + j;
                if (rr < NROWS) {
                    const int f  = (q >> 1) & 1;
                    const int h  = q & 1;
                    const int ri = R0 - KR + rr;
                    float* ldsbase = f ? &rowB[j][OFF + h * 256]
                                       : &rowA[j][OFF + h * 256];
                    if (ri >= 0 && ri < IMG_H) {
                        const float* gsrc = (f ? hp : xp)
                            + (size_t)ri * IMG_W + h * 256 + lane * 4;
                        __builtin_amdgcn_global_load_lds(
                            (const __attribute__((address_space(1))) void*)gsrc,
                            (__attribute__((address_space(3))) void*)ldsbase,
                            16, 0, 0);
                    } else {
                        *(float4*)(ldsbase + lane * 4) =
                            make_float4(0.f, 0.f, 0.f, 0.f);
                    }
                }
            }
        }
        __syncthreads();   // barrier waits vmcnt(0): chunk staged

        // ---- compute 11 rows; ring slot == p (compile-time) ----
        #pragma unroll
        for (int p = 0; p < CH; ++p) {
            const int rr = chk * CH + p;          // block-uniform
            if (rr < NROWS) {
                // window cols [c-6, c+6) as 6 aligned float2 (ds_read_b64);
                // tap t (col c-5+t) is element t+1
                const int ib = OFF + c - 6;       // even -> 8B-aligned
                float wa[12], wb[12];
                #pragma unroll
                for (int m = 0; m < 6; ++m) {
                    const float2 ta = *(const float2*)&rowA[p][ib + 2 * m];
                    const float2 tb = *(const float2*)&rowB[p][ib + 2 * m];
                    wa[2 * m] = ta.x; wa[2 * m + 1] = ta.y;
                    wb[2 * m] = tb.x; wb[2 * m + 1] = tb.y;
                }

                // ---- horizontal pass: 4 raw fields -> ring slot p ----
                float hU = 0.f, hV = 0.f, hS = 0.f, hP = 0.f;
                #pragma unroll
                for (int t = 0; t < KS; ++t) {
                    const float w  = g[t];
                    const float pa = wa[t + 1];
                    const float pb = wb[t + 1];
                    const float papa = pa * pa;
                    const float sq   = fmaf(pb, pb, papa);   // x^2 + xhat^2
                    const float pab  = pa * pb;
                    hU = fmaf(w, pa,  hU);
                    hV = fmaf(w, pb,  hV);
                    hS = fmaf(w, sq,  hS);
                    hP = fmaf(w, pab, hP);
                }
                hist[0][p] = hU; hist[1][p] = hV;
                hist[2][p] = hS; hist[3][p] = hP;

                // ---- vertical pass + SSIM once ring is full ----
                if (rr >= 2 * KR) {
                    float U = 0.f, V = 0.f, S = 0.f, P = 0.f;
                    #pragma unroll
                    for (int t = 0; t < KS; ++t) {
                        const int slot = (p + 1 + t) % KS;   // compile-time
                        const float w = g[t];
                        U = fmaf(w, hist[0][slot], U);
                        V = fmaf(w, hist[1][slot], V);
                        S = fmaf(w, hist[2][slot], S);
                        P = fmaf(w, hist[3][slot], P);
                    }
                    // epilogue on raw-field moments (shift folded in):
                    //   mu_x=(U+1)/2, 2 mu_x mu_y + C1 = 0.5 pU pV + C1
                    //   2 sig_xy + C2 = 0.5 (P - U V) + C2
                    //   mu_x^2+mu_y^2+C1 = 0.25 (pU^2 + pV^2) + C1
                    //   sig_x+sig_y+C2  = 0.25 (S - U^2 - V^2) + C2
                    const float pU = U + 1.f, pV = V + 1.f;
                    const float t1 = fmaf(0.5f,  pU * pV,              C1);
                    const float t2 = fmaf(0.5f,  fmaf(-U, V, P),       C2);
                    const float t3 = fmaf(0.25f, fmaf(pU, pU, pV * pV), C1);
                    const float e  = fmaf(-V, V, fmaf(-U, U, S));
                    const float t4 = fmaf(0.25f, e,                    C2);
                    acc = fmaf(t1 * t2,
                               __builtin_amdgcn_rcpf(fmaf(t3, t4, 1e-8f)),
                               acc);
                }
            }
        }
    }

    // ---- block reduction: wave shuffle, then LDS across the 8 waves ----
    #pragma unroll
    for (int o = 32; o > 0; o >>= 1) acc += __shfl_down(acc, o, 64);
    if (lane == 0) red[wid] = acc;
    __syncthreads();
    if (tid == 0) {
        float s = 0.f;
        #pragma unroll
        for (int w = 0; w < 8; ++w) s += red[w];
        atomicAdd(accum, s);
    }
}

__global__ void ssim_final(const float* __restrict__ accum,
                           float* __restrict__ out)
{
    out[0] = 1.0f - accum[0] * (1.0f / (64.0f * 512.0f * 512.0f));
}

extern "C" void kernel_launch(void* const* d_in, const int* in_sizes, int n_in,
                              void* d_out, int out_size, void* d_ws, size_t ws_size,
                              hipStream_t stream) {
    const float* xhat = (const float*)d_in[0];
    const float* xin  = (const float*)d_in[1];
    const float* kern = (const float*)d_in[2];
    float* out = (float*)d_out;
    float* ws  = (float*)d_ws;

    const int nimg   = in_sizes[0] / (IMG_W * IMG_H);   // 64
    const int strips = IMG_H / RH;                      // 8
    const int nblk   = nimg * strips;                   // 512 = 2 blocks/CU

    hipMemsetAsync(ws, 0, sizeof(float), stream);
    ssim_main<<<nblk, 512, 0, stream>>>(xhat, xin, kern, ws);
    ssim_final<<<1, 1, 0, stream>>>(ws, out);
}

// Round 7
// 205.538 us; speedup vs baseline: 2.0998x; 1.0192x over previous
//
#include <hip/hip_runtime.h>
#include <stdint.h>

#define IMG_W 512
#define IMG_H 512
#define RH    64            // output rows per block-strip
#define KS    11
#define KR    5
#define OFF   8             // LDS left pad (16B-aligned, stays zero)
#define LROW  (OFF + IMG_W + OFF)   // 528 floats per row buffer
#define CH    KS            // 11 rows per barrier pair (ring-aligned)
#define NROWS (RH + 2*KR)   // 74 input rows per strip
#define NCH   7             // 7*11 = 77 >= 74

typedef float v2f __attribute__((ext_vector_type(2)));

// One block = 512 threads (8 waves), one 64-row x 512-col strip, 1 col/thread.
// Staging is direct global->LDS (global_load_lds_dwordx4) of RAW values; the
// (v+1)/2 shift is folded into the epilogue analytically. 4-field ring held as
// packed pairs (U,V) and (S,P):
//   U = conv(x), V = conv(xhat), S = conv(x^2 + xhat^2), P = conv(x*xhat)
// Vertical 11-tap runs on v_pk_fma_f32 (dual-f32: 22 instr instead of 44),
// weights broadcast from SGPR pairs (g,g). Ring phase p is compile-time.
// __launch_bounds__(512,2): 256-reg budget so the ring stays in arch VGPRs —
// at (512,3)/(512,4) the allocator put it in AGPRs (~48 v_accvgpr moves/row
// and occupancy fell to 1 block/CU).
__global__ __launch_bounds__(512, 2)
void ssim_main(const float* __restrict__ xhat,
               const float* __restrict__ x,
               const float* __restrict__ kern,
               float* __restrict__ accum)
{
    __shared__ float rowA[CH][LROW];   // raw x rows, zero-padded cols
    __shared__ float rowB[CH][LROW];   // raw xhat rows
    __shared__ float red[8];

    const int tid   = threadIdx.x;
    const int lane  = tid & 63;
    const int wid   = tid >> 6;          // 8 waves
    const int c     = tid;               // this thread's column
    const int img   = blockIdx.x >> 3;   // 8 strips per image
    const int strip = blockIdx.x & 7;
    const int R0    = strip * RH;
    const float* xp = x    + (size_t)img * (IMG_W * IMG_H);
    const float* hp = xhat + (size_t)img * (IMG_W * IMG_H);

    // Separable 1D weights g[i] = k[5][i]/sqrt(k[5][5]); lane-uniform ->
    // pinned to SGPRs via readfirstlane. gg[i] = (g,g) as an SGPR pair for
    // the packed vertical pass.
    float  g[KS];
    double gg[KS];
    {
        const float inv = rsqrtf(kern[5 * KS + 5]);
        #pragma unroll
        for (int i = 0; i < KS; ++i) {
            const float v = kern[5 * KS + i] * inv;
            const uint32_t ub = __builtin_amdgcn_readfirstlane(
                                    __builtin_bit_cast(int, v));
            g[i]  = __builtin_bit_cast(float, ub);
            const uint64_t uu = ((uint64_t)ub << 32) | (uint64_t)ub;
            gg[i] = __builtin_bit_cast(double, uu);
        }
    }

    // zero all LDS once (pads must stay 0; interior overwritten each chunk)
    {
        float4* a4 = (float4*)&rowA[0][0];
        float4* b4 = (float4*)&rowB[0][0];
        #pragma unroll 1
        for (int i = tid; i < (CH * LROW) / 4; i += 512) {
            a4[i] = make_float4(0.f, 0.f, 0.f, 0.f);
            b4[i] = make_float4(0.f, 0.f, 0.f, 0.f);
        }
    }

    // ring of horizontally-convolved rows: 2 pair-fields x 11 rows (44 VGPRs)
    v2f uvR[KS];   // (U, V)
    v2f spR[KS];   // (S, P)
    float acc = 0.f;
    const float C1 = 1e-4f, C2 = 9e-4f;

    #pragma unroll 1
    for (int chk = 0; chk < NCH; ++chk) {
        __syncthreads();   // previous chunk fully consumed (also covers zero-init)

        // ---- stage 11 rows x 2 fields, direct global->LDS ----
        // 44 issues = row j (0..10) x field f (A,B) x half h (0,1); wave w
        // takes q = w, w+8, ... Each issue: 64 lanes x 16B, coalesced; LDS
        // dest is wave-uniform base + lane*16 (linear layout).
        #pragma unroll
        for (int k = 0; k < 6; ++k) {
            const int q = wid + 8 * k;           // wave-uniform
            if (q < 4 * CH) {
                const int j  = q >> 2;
                const int rr = chk * CH + j;
                if (rr < NROWS) {
                    const int f  = (q >> 1) & 1;
                    const int h  = q & 1;
                    const int ri = R0 - KR + rr;
                    float* ldsbase = f ? &rowB[j][OFF + h * 256]
                                       : &rowA[j][OFF + h * 256];
                    if (ri >= 0 && ri < IMG_H) {
                        const float* gsrc = (f ? hp : xp)
                            + (size_t)ri * IMG_W + h * 256 + lane * 4;
                        __builtin_amdgcn_global_load_lds(
                            (const __attribute__((address_space(1))) void*)gsrc,
                            (__attribute__((address_space(3))) void*)ldsbase,
                            16, 0, 0);
                    } else {
                        *(float4*)(ldsbase + lane * 4) =
                            make_float4(0.f, 0.f, 0.f, 0.f);
                    }
                }
            }
        }
        __syncthreads();   // barrier waits vmcnt(0): chunk staged

        // ---- compute 11 rows; ring slot == p (compile-time) ----
        #pragma unroll
        for (int p = 0; p < CH; ++p) {
            const int rr = chk * CH + p;          // block-uniform
            if (rr < NROWS) {
                // window cols [c-6, c+6) as 6 aligned float2 (ds_read_b64);
                // tap t (col c-5+t) is element t+1
                const int ib = OFF + c - 6;       // even -> 8B-aligned
                float wa[12], wb[12];
                #pragma unroll
                for (int m = 0; m < 6; ++m) {
                    const float2 ta = *(const float2*)&rowA[p][ib + 2 * m];
                    const float2 tb = *(const float2*)&rowB[p][ib + 2 * m];
                    wa[2 * m] = ta.x; wa[2 * m + 1] = ta.y;
                    wb[2 * m] = tb.x; wb[2 * m + 1] = tb.y;
                }

                // ---- horizontal pass: accumulate into pair elements ----
                v2f huv; huv.x = 0.f; huv.y = 0.f;   // (U, V)
                v2f hsp; hsp.x = 0.f; hsp.y = 0.f;   // (S, P)
                #pragma unroll
                for (int t = 0; t < KS; ++t) {
                    const float w  = g[t];
                    const float pa = wa[t + 1];
                    const float pb = wb[t + 1];
                    const float papa = pa * pa;
                    const float sq   = fmaf(pb, pb, papa);   // x^2 + xhat^2
                    const float pab  = pa * pb;
                    huv.x = fmaf(w, pa,  huv.x);
                    huv.y = fmaf(w, pb,  huv.y);
                    hsp.x = fmaf(w, sq,  hsp.x);
                    hsp.y = fmaf(w, pab, hsp.y);
                }
                uvR[p] = huv;
                spR[p] = hsp;

                // ---- vertical pass (packed dual-f32) + SSIM ----
                if (rr >= 2 * KR) {
                    v2f UV; UV.x = 0.f; UV.y = 0.f;
                    v2f SP; SP.x = 0.f; SP.y = 0.f;
                    #pragma unroll
                    for (int t = 0; t < KS; ++t) {
                        const int slot = (p + 1 + t) % KS;   // compile-time
                        asm("v_pk_fma_f32 %0, %1, %2, %0"
                            : "+v"(UV) : "s"(gg[t]), "v"(uvR[slot]));
                        asm("v_pk_fma_f32 %0, %1, %2, %0"
                            : "+v"(SP) : "s"(gg[t]), "v"(spR[slot]));
                    }
                    const float U = UV.x, V = UV.y, S = SP.x, P = SP.y;
                    // epilogue on raw-field moments (shift folded in):
                    //   2 mu_x mu_y + C1   = 0.5 pU pV + C1
                    //   2 sig_xy + C2      = 0.5 (P - U V) + C2
                    //   mu_x^2+mu_y^2+C1   = 0.25 (pU^2 + pV^2) + C1
                    //   sig_x+sig_y+C2     = 0.25 (S - U^2 - V^2) + C2
                    const float pU = U + 1.f, pV = V + 1.f;
                    const float t1 = fmaf(0.5f,  pU * pV,              C1);
                    const float t2 = fmaf(0.5f,  fmaf(-U, V, P),       C2);
                    const float t3 = fmaf(0.25f, fmaf(pU, pU, pV * pV), C1);
                    const float e  = fmaf(-V, V, fmaf(-U, U, S));
                    const float t4 = fmaf(0.25f, e,                    C2);
                    acc = fmaf(t1 * t2,
                               __builtin_amdgcn_rcpf(fmaf(t3, t4, 1e-8f)),
                               acc);
                }
            }
        }
    }

    // ---- block reduction: wave shuffle, then LDS across the 8 waves ----
    #pragma unroll
    for (int o = 32; o > 0; o >>= 1) acc += __shfl_down(acc, o, 64);
    if (lane == 0) red[wid] = acc;
    __syncthreads();
    if (tid == 0) {
        float s = 0.f;
        #pragma unroll
        for (int w = 0; w < 8; ++w) s += red[w];
        atomicAdd(accum, s);
    }
}

__global__ void ssim_final(const float* __restrict__ accum,
                           float* __restrict__ out)
{
    out[0] = 1.0f - accum[0] * (1.0f / (64.0f * 512.0f * 512.0f));
}

extern "C" void kernel_launch(void* const* d_in, const int* in_sizes, int n_in,
                              void* d_out, int out_size, void* d_ws, size_t ws_size,
                              hipStream_t stream) {
    const float* xhat = (const float*)d_in[0];
    const float* xin  = (const float*)d_in[1];
    const float* kern = (const float*)d_in[2];
    float* out = (float*)d_out;
    float* ws  = (float*)d_ws;

    const int nimg   = in_sizes[0] / (IMG_W * IMG_H);   // 64
    const int strips = IMG_H / RH;                      // 8
    const int nblk   = nimg * strips;                   // 512 = 2 blocks/CU

    hipMemsetAsync(ws, 0, sizeof(float), stream);
    ssim_main<<<nblk, 512, 0, stream>>>(xhat, xin, kern, ws);
    ssim_final<<<1, 1, 0, stream>>>(ws, out);
}

// Round 9
// 200.639 us; speedup vs baseline: 2.1511x; 1.0244x over previous
//
#include <hip/hip_runtime.h>
#include <stdint.h>

#define IMG_W 512
#define IMG_H 512
#define RH    64            // output rows per block-strip
#define KS    11
#define KR    5
#define OFF   8             // LDS left pad (16B-aligned, stays zero)
#define LROW  (OFF + IMG_W + OFF)   // 528 floats per row buffer
#define CH    KS            // 11 rows per chunk (ring-aligned)
#define NROWS (RH + 2*KR)   // 74 input rows per strip
#define NCH   7             // 7*11 = 77 >= 74

typedef float v2f __attribute__((ext_vector_type(2)));

// One block = 512 threads (8 waves), one 64-row x 512-col strip, 1 col/thread.
// DOUBLE-BUFFERED chunk pipeline: chunk c+1's global->LDS loads are issued at
// the start of the body, 11 rows of chunk c are computed, then ONE barrier per
// chunk. The barrier's implicit vmcnt(0) drain is free: the prefetch was
// issued a full compute-phase (~2500 cyc) earlier. Staging is raw values
// (shift folded into epilogue); 4-field ring as packed pairs (U,V),(S,P):
//   U = conv(x), V = conv(xhat), S = conv(x^2 + xhat^2), P = conv(x*xhat)
// Vertical 11-tap on v_pk_fma_f32, weights broadcast from SGPR pairs (g,g).
// __launch_bounds__(512,2): 256-reg budget keeps the ring in arch VGPRs.
__global__ __launch_bounds__(512, 2)
void ssim_main(const float* __restrict__ xhat,
               const float* __restrict__ x,
               const float* __restrict__ kern,
               float* __restrict__ accum)
{
    __shared__ float rowA[2][CH][LROW];   // raw x rows, zero-padded cols
    __shared__ float rowB[2][CH][LROW];   // raw xhat rows
    __shared__ float red[8];

    const int tid   = threadIdx.x;
    const int lane  = tid & 63;
    const int wid   = tid >> 6;          // 8 waves
    const int c     = tid;               // this thread's column
    const int img   = blockIdx.x >> 3;   // 8 strips per image
    const int strip = blockIdx.x & 7;
    const int R0    = strip * RH;
    const float* xp = x    + (size_t)img * (IMG_W * IMG_H);
    const float* hp = xhat + (size_t)img * (IMG_W * IMG_H);

    // Separable 1D weights g[i] = k[5][i]/sqrt(k[5][5]); lane-uniform ->
    // pinned to SGPRs via readfirstlane. gg[i] = (g,g) SGPR pair for pk_fma.
    float  g[KS];
    double gg[KS];
    {
        const float inv = rsqrtf(kern[5 * KS + 5]);
        #pragma unroll
        for (int i = 0; i < KS; ++i) {
            const float v = kern[5 * KS + i] * inv;
            const uint32_t ub = __builtin_amdgcn_readfirstlane(
                                    __builtin_bit_cast(int, v));
            g[i]  = __builtin_bit_cast(float, ub);
            const uint64_t uu = ((uint64_t)ub << 32) | (uint64_t)ub;
            gg[i] = __builtin_bit_cast(double, uu);
        }
    }

    // zero all LDS once (pads must stay 0; interior overwritten each stage)
    {
        float4* a4 = (float4*)&rowA[0][0][0];
        float4* b4 = (float4*)&rowB[0][0][0];
        #pragma unroll 1
        for (int i = tid; i < (2 * CH * LROW) / 4; i += 512) {
            a4[i] = make_float4(0.f, 0.f, 0.f, 0.f);
            b4[i] = make_float4(0.f, 0.f, 0.f, 0.f);
        }
    }

    // stage one chunk into buffer `buf`: 44 issues = row j x field f x half h;
    // wave w takes q = w, w+8, ... Each issue: 64 lanes x 16B, coalesced; LDS
    // dest is wave-uniform base + lane*16 (linear layout). Zero VGPR cost.
    auto stage = [&](int buf, int chkIdx) {
        #pragma unroll
        for (int k = 0; k < 6; ++k) {
            const int q = wid + 8 * k;           // wave-uniform
            if (q < 4 * CH) {
                const int j  = q >> 2;
                const int rr = chkIdx * CH + j;
                if (rr < NROWS) {
                    const int f  = (q >> 1) & 1;
                    const int h  = q & 1;
                    const int ri = R0 - KR + rr;
                    float* ldsbase = f ? &rowB[buf][j][OFF + h * 256]
                                       : &rowA[buf][j][OFF + h * 256];
                    if (ri >= 0 && ri < IMG_H) {
                        const float* gsrc = (f ? hp : xp)
                            + (size_t)ri * IMG_W + h * 256 + lane * 4;
                        __builtin_amdgcn_global_load_lds(
                            (const __attribute__((address_space(1))) void*)gsrc,
                            (__attribute__((address_space(3))) void*)ldsbase,
                            16, 0, 0);
                    } else {
                        *(float4*)(ldsbase + lane * 4) =
                            make_float4(0.f, 0.f, 0.f, 0.f);
                    }
                }
            }
        }
    };

    // ring of horizontally-convolved rows: 2 pair-fields x 11 rows (44 VGPRs)
    v2f uvR[KS];   // (U, V)
    v2f spR[KS];   // (S, P)
    float acc = 0.f;
    const float C1 = 1e-4f, C2 = 9e-4f;

    // ---- prologue: stage chunk 0 into buf 0 ----
    stage(0, 0);
    __syncthreads();   // zero-init + chunk 0 staged (compiler drains vmcnt/lgkm)

    int cur = 0;
    #pragma unroll 1
    for (int chk = 0; chk < NCH; ++chk) {
        // ---- prefetch next chunk into the other buffer; latency hides under
        //      the 11-row compute below ----
        if (chk + 1 < NCH) stage(cur ^ 1, chk + 1);

        // ---- compute 11 rows; ring slot == p (compile-time) ----
        #pragma unroll
        for (int p = 0; p < CH; ++p) {
            const int rr = chk * CH + p;          // block-uniform
            if (rr < NROWS) {
                // window cols [c-6, c+6) as 6 aligned float2 (ds_read_b64);
                // tap t (col c-5+t) is element t+1
                const int ib = OFF + c - 6;       // even -> 8B-aligned
                float wa[12], wb[12];
                #pragma unroll
                for (int m = 0; m < 6; ++m) {
                    const float2 ta = *(const float2*)&rowA[cur][p][ib + 2 * m];
                    const float2 tb = *(const float2*)&rowB[cur][p][ib + 2 * m];
                    wa[2 * m] = ta.x; wa[2 * m + 1] = ta.y;
                    wb[2 * m] = tb.x; wb[2 * m + 1] = tb.y;
                }

                // ---- horizontal pass: accumulate into pair elements ----
                v2f huv; huv.x = 0.f; huv.y = 0.f;   // (U, V)
                v2f hsp; hsp.x = 0.f; hsp.y = 0.f;   // (S, P)
                #pragma unroll
                for (int t = 0; t < KS; ++t) {
                    const float w  = g[t];
                    const float pa = wa[t + 1];
                    const float pb = wb[t + 1];
                    const float papa = pa * pa;
                    const float sq   = fmaf(pb, pb, papa);   // x^2 + xhat^2
                    const float pab  = pa * pb;
                    huv.x = fmaf(w, pa,  huv.x);
                    huv.y = fmaf(w, pb,  huv.y);
                    hsp.x = fmaf(w, sq,  hsp.x);
                    hsp.y = fmaf(w, pab, hsp.y);
                }
                uvR[p] = huv;
                spR[p] = hsp;

                // ---- vertical pass (packed dual-f32) + SSIM ----
                if (rr >= 2 * KR) {
                    v2f UV; UV.x = 0.f; UV.y = 0.f;
                    v2f SP; SP.x = 0.f; SP.y = 0.f;
                    #pragma unroll
                    for (int t = 0; t < KS; ++t) {
                        const int slot = (p + 1 + t) % KS;   // compile-time
                        asm("v_pk_fma_f32 %0, %1, %2, %0"
                            : "+v"(UV) : "s"(gg[t]), "v"(uvR[slot]));
                        asm("v_pk_fma_f32 %0, %1, %2, %0"
                            : "+v"(SP) : "s"(gg[t]), "v"(spR[slot]));
                    }
                    const float U = UV.x, V = UV.y, S = SP.x, P = SP.y;
                    // epilogue on raw-field moments (shift folded in):
                    //   2 mu_x mu_y + C1   = 0.5 pU pV + C1
                    //   2 sig_xy + C2      = 0.5 (P - U V) + C2
                    //   mu_x^2+mu_y^2+C1   = 0.25 (pU^2 + pV^2) + C1
                    //   sig_x+sig_y+C2     = 0.25 (S - U^2 - V^2) + C2
                    const float pU = U + 1.f, pV = V + 1.f;
                    const float t1 = fmaf(0.5f,  pU * pV,              C1);
                    const float t2 = fmaf(0.5f,  fmaf(-U, V, P),       C2);
                    const float t3 = fmaf(0.25f, fmaf(pU, pU, pV * pV), C1);
                    const float e  = fmaf(-V, V, fmaf(-U, U, S));
                    const float t4 = fmaf(0.25f, e,                    C2);
                    acc = fmaf(t1 * t2,
                               __builtin_amdgcn_rcpf(fmaf(t3, t4, 1e-8f)),
                               acc);
                }
            }
        }

        // ONE barrier per chunk: waits this chunk's prefetch (landed long ago)
        // and ensures all waves are done reading buf[cur] before it is
        // overwritten next iteration.
        __syncthreads();
        cur ^= 1;
    }

    // ---- block reduction: wave shuffle, then LDS across the 8 waves ----
    #pragma unroll
    for (int o = 32; o > 0; o >>= 1) acc += __shfl_down(acc, o, 64);
    if (lane == 0) red[wid] = acc;
    __syncthreads();
    if (tid == 0) {
        float s = 0.f;
        #pragma unroll
        for (int w = 0; w < 8; ++w) s += red[w];
        atomicAdd(accum, s);
    }
}

__global__ void ssim_final(const float* __restrict__ accum,
                           float* __restrict__ out)
{
    out[0] = 1.0f - accum[0] * (1.0f / (64.0f * 512.0f * 512.0f));
}

extern "C" void kernel_launch(void* const* d_in, const int* in_sizes, int n_in,
                              void* d_out, int out_size, void* d_ws, size_t ws_size,
                              hipStream_t stream) {
    const float* xhat = (const float*)d_in[0];
    const float* xin  = (const float*)d_in[1];
    const float* kern = (const float*)d_in[2];
    float* out = (float*)d_out;
    float* ws  = (float*)d_ws;

    const int nimg   = in_sizes[0] / (IMG_W * IMG_H);   // 64
    const int strips = IMG_H / RH;                      // 8
    const int nblk   = nimg * strips;                   // 512 = 2 blocks/CU

    hipMemsetAsync(ws, 0, sizeof(float), stream);
    ssim_main<<<nblk, 512, 0, stream>>>(xhat, xin, kern, ws);
    ssim_final<<<1, 1, 0, stream>>>(ws, out);
}